// Round 15
// baseline (419.566 us; speedup 1.0000x reference)
//
#include <hip/hip_runtime.h>
#include <math.h>

constexpr int NN   = 50000;   // nodes
constexpr int NE   = 400000;  // edges
constexpr int INC  = 128;     // in channels
constexpr int NH   = 4;       // heads
constexpr int D1   = 256;     // NH*HIDC
constexpr int D4   = 1024;    // 4*D1 fused QKVS logical cols
constexpr int NOUT = 10;      // classes
constexpr int NG   = 64;      // graphs
constexpr int NB_SCAN = (NN + 255) / 256;   // 196 scan blocks

// GEMM output split per node:
//   QS[node][512] bf16 : cols 0..255 = Q, cols 256..511 = S
//   KV8[node][512] fp8 : byte j -> group g=j>>3, off=j&7: off<4 -> K ch 4g+off,
//                                                        off>=4 -> V ch 4g+(off-4)
// Lane t of node_attn reads 8 B at node*512 + t*8 = [K c0..c0+3 | V c0..c0+3].

typedef __attribute__((ext_vector_type(8))) short bf16x8;   // MFMA A/B frag
typedef __attribute__((ext_vector_type(4))) float f32x4;    // MFMA C/D frag
typedef __attribute__((ext_vector_type(2))) float f32x2;

// ---------- bf16 helpers ----------
__device__ __forceinline__ short f2b(float f) {
  union { float f; unsigned int i; } v; v.f = f;
  unsigned int x = v.i;
  return (short)((x + 0x7FFFu + ((x >> 16) & 1u)) >> 16);
}
__device__ __forceinline__ float b2f(short u) {
  union { unsigned int i; float f; } v; v.i = ((unsigned int)(unsigned short)u) << 16;
  return v.f;
}
__device__ __forceinline__ float4 ld4b(const short* p) {
  short4 u = *(const short4*)p;
  return make_float4(b2f(u.x), b2f(u.y), b2f(u.z), b2f(u.w));
}
__device__ __forceinline__ void unpack8(const int4 v, float* f) {
  union { unsigned int u; float x; } a;
  a.u = (unsigned int)v.x << 16;         f[0] = a.x;
  a.u = (unsigned int)v.x & 0xffff0000u; f[1] = a.x;
  a.u = (unsigned int)v.y << 16;         f[2] = a.x;
  a.u = (unsigned int)v.y & 0xffff0000u; f[3] = a.x;
  a.u = (unsigned int)v.z << 16;         f[4] = a.x;
  a.u = (unsigned int)v.z & 0xffff0000u; f[5] = a.x;
  a.u = (unsigned int)v.w << 16;         f[6] = a.x;
  a.u = (unsigned int)v.w & 0xffff0000u; f[7] = a.x;
}
// pack 4 floats -> 4 fp8 e4m3 bytes (HW convert)
__device__ __forceinline__ int pk_fp8x4(float a, float b, float c, float d) {
  int v = __builtin_amdgcn_cvt_pk_fp8_f32(a, b, 0, false);
  v = __builtin_amdgcn_cvt_pk_fp8_f32(c, d, v, true);
  return v;
}

// ---------- async global->LDS 16B ----------
__device__ __forceinline__ void gld_lds16(const short* g, short* l) {
  __builtin_amdgcn_global_load_lds(
      (const __attribute__((address_space(1))) unsigned int*)g,
      (__attribute__((address_space(3))) unsigned int*)l, 16, 0, 0);
}

// ---------- fused converts + zeroing (one dispatch) ----------
constexpr int CVT_XB  = (NN * INC / 4 + 255) / 256;   // 6250 blocks
constexpr int CVT_W1B = (4 * D1 * INC + 255) / 256;   // 512
constexpr int CVT_W2B = (4 * D1 * D1 + 255) / 256;    // 1024
constexpr int CVT_BB  = 8;                            // bias blocks
constexpr int CVT_DB  = (NN + 255) / 256;             // deg zero (196)
constexpr int CVT_SB  = (NG * D1 + 255) / 256;        // sums zero (64)

__device__ __forceinline__ void wt_one(const float* Wq, const float* Wk,
    const float* Wv, const float* Ws, short* Wt, int kbits, int i) {
  int K = 1 << kbits;
  int seg = i >> (kbits + 8);               // 0=Q 1=K 2=V 3=S
  int idx = i & ((D1 << kbits) - 1);
  int n = idx >> kbits, k = idx & (K - 1);
  const float* W = (seg == 0) ? Wq : (seg == 1) ? Wk : (seg == 2) ? Wv : Ws;
  int row;
  if (seg == 0)      row = n;
  else if (seg == 3) row = 768 + n;
  else               row = 256 + (n >> 2) * 8 + ((seg == 2) ? 4 : 0) + (n & 3);
  Wt[(size_t)row * K + k] = f2b(W[(size_t)k * D1 + n]);
}

__global__ void cvt_all_k(const float* __restrict__ x, short* __restrict__ Xb,
    const float* __restrict__ Wq1, const float* __restrict__ Wk1,
    const float* __restrict__ Wv1, const float* __restrict__ Ws1,
    const float* __restrict__ Wq2, const float* __restrict__ Wk2,
    const float* __restrict__ Wv2, const float* __restrict__ Ws2,
    short* __restrict__ Wtc1, short* __restrict__ Wtc2,
    const float* __restrict__ bq1, const float* __restrict__ bk1,
    const float* __restrict__ bv1, const float* __restrict__ bs1,
    const float* __restrict__ bq2, const float* __restrict__ bk2,
    const float* __restrict__ bv2, const float* __restrict__ bs2,
    float* __restrict__ bc1, float* __restrict__ bc2,
    int* __restrict__ deg, float* __restrict__ sums) {
  const int b = blockIdx.x;
  const int t = threadIdx.x;
  if (b < CVT_XB) {                               // x -> bf16 (4/thread)
    int i = (b * 256 + t) * 4;
    if (i >= NN * INC) return;
    float4 v = *(const float4*)(x + i);
    short4 o; o.x = f2b(v.x); o.y = f2b(v.y); o.z = f2b(v.z); o.w = f2b(v.w);
    *(short4*)(Xb + i) = o;
  } else if (b < CVT_XB + CVT_W1B) {              // layer-1 weights
    int i = (b - CVT_XB) * 256 + t;
    if (i < 4 * D1 * INC) wt_one(Wq1, Wk1, Wv1, Ws1, Wtc1, 7, i);
  } else if (b < CVT_XB + CVT_W1B + CVT_W2B) {    // layer-2 weights
    int i = (b - CVT_XB - CVT_W1B) * 256 + t;
    if (i < 4 * D1 * D1) wt_one(Wq2, Wk2, Wv2, Ws2, Wtc2, 8, i);
  } else if (b < CVT_XB + CVT_W1B + CVT_W2B + CVT_BB) {  // bias concat
    int i = (b - CVT_XB - CVT_W1B - CVT_W2B) * 256 + t;
    if (i >= 2 * D4) return;
    int row = i & (D4 - 1);
    const float* bq = (i < D4) ? bq1 : bq2;
    const float* bk = (i < D4) ? bk1 : bk2;
    const float* bv = (i < D4) ? bv1 : bv2;
    const float* bs = (i < D4) ? bs1 : bs2;
    float v;
    if (row < 256) v = bq[row];
    else if (row < 768) {
      int j = row - 256, grp = j >> 3, off = j & 7;
      int ch = grp * 4 + (off & 3);
      v = (off < 4) ? bk[ch] : bv[ch];
    } else v = bs[row - 768];
    ((i < D4) ? bc1 : bc2)[row] = v;
  } else if (b < CVT_XB + CVT_W1B + CVT_W2B + CVT_BB + CVT_DB) {  // deg = 0
    int i = (b - CVT_XB - CVT_W1B - CVT_W2B - CVT_BB) * 256 + t;
    if (i < NN) deg[i] = 0;
  } else {                                        // sums = 0
    int i = (b - CVT_XB - CVT_W1B - CVT_W2B - CVT_BB - CVT_DB) * 256 + t;
    if (i < NG * D1) sums[i] = 0.f;
  }
}

// ---------- CSR build ----------
__global__ void deg_count(const int* __restrict__ dst, int* __restrict__ deg) {
  int e = blockIdx.x * 256 + threadIdx.x;
  if (e < NE) atomicAdd(&deg[dst[e]], 1);
}
// block partial sums; extra block NB_SCAN does graph bounds (binary search)
__global__ __launch_bounds__(256) void scan1(const int* __restrict__ deg,
    int* __restrict__ partial, const int* __restrict__ batch, int* __restrict__ gb) {
  if (blockIdx.x == NB_SCAN) {
    int g = threadIdx.x;
    if (g > NG) return;
    int lo = 0, hi = NN;
    while (lo < hi) {
      int mid = (lo + hi) >> 1;
      if (batch[mid] < g) lo = mid + 1; else hi = mid;
    }
    gb[g] = lo;
    return;
  }
  __shared__ int sh[256];
  int t = threadIdx.x, i = blockIdx.x * 256 + t;
  sh[t] = (i < NN) ? deg[i] : 0;
  __syncthreads();
  for (int off = 128; off > 0; off >>= 1) {
    if (t < off) sh[t] += sh[t + off];
    __syncthreads();
  }
  if (t == 0) partial[blockIdx.x] = sh[0];
}
__global__ __launch_bounds__(256) void scan3(const int* __restrict__ deg,
    const int* __restrict__ partial, int* __restrict__ rowstart,
    int* __restrict__ cursor) {
  __shared__ int sh[256];
  __shared__ int base_s;
  const int t = threadIdx.x;
  int pv = (t < NB_SCAN) ? partial[t] : 0;
  sh[t] = pv;
  __syncthreads();
  for (int off = 1; off < 256; off <<= 1) {
    int o = (t >= off) ? sh[t - off] : 0;
    __syncthreads();
    sh[t] += o;
    __syncthreads();
  }
  if (t == 0) base_s = (blockIdx.x == 0) ? 0 : sh[blockIdx.x - 1];
  __syncthreads();
  const int base = base_s;
  __syncthreads();
  int i = blockIdx.x * 256 + t;
  int v = (i < NN) ? deg[i] : 0;
  sh[t] = v;
  __syncthreads();
  for (int off = 1; off < 256; off <<= 1) {
    int o = (t >= off) ? sh[t - off] : 0;
    __syncthreads();
    sh[t] += o;
    __syncthreads();
  }
  int excl = sh[t] - v + base;
  if (i <= NN) rowstart[i] = excl;
  if (i < NN)  cursor[i]   = excl;
}
__global__ void scatter_k(const int* __restrict__ src, const int* __restrict__ dst,
    int* __restrict__ cursor, int* __restrict__ esrc) {
  int e = blockIdx.x * 256 + threadIdx.x;
  if (e >= NE) return;
  int d = dst[e];
  int pos = atomicAdd(&cursor[d], 1);
  esrc[pos] = src[e];
}

// ---------- MFMA GEMM: [QS bf16 | KV8 fp8] = Xb[M,K] @ Wt[1024,K]^T + bias ----
constexpr int CLDS = 136;   // C-tile LDS stride in shorts

__global__ __launch_bounds__(256) void gemm_mfma(
    const short* __restrict__ Xb, const short* __restrict__ Wt,
    const float* __restrict__ bias, short* __restrict__ QS,
    unsigned char* __restrict__ KV8, int M, int K) {
  __shared__ short smem[128 * CLDS];
  short* As0 = smem;
  short* As1 = smem + 4096;
  short* Bs0 = smem + 8192;
  short* Bs1 = smem + 12288;
  const int bx = blockIdx.x;                 // 0..63
  const int by = blockIdx.y;
  const int m_tile = (bx & 7) + (by << 3);   // XCD swizzle
  const int n_tile = bx >> 3;                // 0..7
  const int m0 = m_tile * 128;
  if (m0 >= M) return;
  const int n0 = n_tile * 128;

  const int t    = threadIdx.x;
  const int lane = t & 63;
  const int wv   = t >> 6;
  const int wm   = (wv >> 1) * 64;
  const int wn   = (wv & 1) * 64;
  const int quad = lane >> 4;
  const int l16  = lane & 15;
  const int lrow = lane >> 2;
  const int lseg = lane & 3;

  f32x4 acc[4][4] = {};
  for (int k0 = 0; k0 < K; k0 += 64) {
#pragma unroll
    for (int j = 0; j < 2; ++j) {
      const int rb = wv * 32 + j * 16;
      int gm = m0 + rb + lrow;
      gm = gm < M ? gm : M - 1;                        // clamp (stores guarded)
      const size_t ga = (size_t)gm * K + k0 + lseg * 8;
      gld_lds16(Xb + ga,      &As0[rb * 32]);
      gld_lds16(Xb + ga + 32, &As1[rb * 32]);
      const size_t gw = (size_t)(n0 + rb + lrow) * K + k0 + lseg * 8;
      gld_lds16(Wt + gw,      &Bs0[rb * 32]);
      gld_lds16(Wt + gw + 32, &Bs1[rb * 32]);
    }
    __syncthreads();
    {
      bf16x8 a[4], b[4];
#pragma unroll
      for (int mi = 0; mi < 4; mi++)
        a[mi] = *(const bf16x8*)(&As0[(wm + mi * 16 + l16) * 32 + quad * 8]);
#pragma unroll
      for (int nj = 0; nj < 4; nj++)
        b[nj] = *(const bf16x8*)(&Bs0[(wn + nj * 16 + l16) * 32 + quad * 8]);
#pragma unroll
      for (int mi = 0; mi < 4; mi++)
#pragma unroll
        for (int nj = 0; nj < 4; nj++)
          acc[mi][nj] = __builtin_amdgcn_mfma_f32_16x16x32_bf16(a[mi], b[nj], acc[mi][nj], 0, 0, 0);
#pragma unroll
      for (int mi = 0; mi < 4; mi++)
        a[mi] = *(const bf16x8*)(&As1[(wm + mi * 16 + l16) * 32 + quad * 8]);
#pragma unroll
      for (int nj = 0; nj < 4; nj++)
        b[nj] = *(const bf16x8*)(&Bs1[(wn + nj * 16 + l16) * 32 + quad * 8]);
#pragma unroll
      for (int mi = 0; mi < 4; mi++)
#pragma unroll
        for (int nj = 0; nj < 4; nj++)
          acc[mi][nj] = __builtin_amdgcn_mfma_f32_16x16x32_bf16(a[mi], b[nj], acc[mi][nj], 0, 0, 0);
    }
    __syncthreads();
  }
  // ---- epilogue: stage bf16 C tile in LDS, then coalesced typed stores ----
  float bcol[4];
#pragma unroll
  for (int nj = 0; nj < 4; nj++) bcol[nj] = bias[n0 + wn + nj * 16 + l16];
#pragma unroll
  for (int mi = 0; mi < 4; mi++)
#pragma unroll
    for (int r = 0; r < 4; r++) {
      const int row = wm + mi * 16 + quad * 4 + r;
#pragma unroll
      for (int nj = 0; nj < 4; nj++)
        smem[row * CLDS + wn + nj * 16 + l16] = f2b(acc[mi][nj][r] + bcol[nj]);
    }
  __syncthreads();
  const bool isKV = (n_tile >= 2) && (n_tile <= 5);
  const int qs_base = (n_tile < 2) ? n0 : (n0 - 512);   // Q cols or S cols
  const int kv_base = n0 - 256;
#pragma unroll
  for (int it = 0; it < 8; ++it) {
    const int chunk = it * 256 + t;          // 2048 chunks of 8 shorts
    const int row = chunk >> 4;
    const int cc  = (chunk & 15) * 8;
    const int gm  = m0 + row;
    if (gm >= M) continue;
    const int4 s4 = *(const int4*)(&smem[row * CLDS + cc]);
    if (isKV) {
      float f[8];
      unpack8(s4, f);
      int lo = pk_fp8x4(f[0], f[1], f[2], f[3]);
      int hi = pk_fp8x4(f[4], f[5], f[6], f[7]);
      *(int2*)(KV8 + (size_t)gm * 512 + kv_base + cc) = make_int2(lo, hi);
    } else {
      *(int4*)(QS + (size_t)gm * 512 + qs_base + cc) = s4;
    }
  }
}

// ---------- fp8 KV decode ----------
__device__ __forceinline__ void dec_kv(const int2 x, float* k, float* v) {
  f32x2 a = __builtin_amdgcn_cvt_pk_f32_fp8(x.x, false);
  f32x2 b = __builtin_amdgcn_cvt_pk_f32_fp8(x.x, true);
  f32x2 c = __builtin_amdgcn_cvt_pk_f32_fp8(x.y, false);
  f32x2 d = __builtin_amdgcn_cvt_pk_f32_fp8(x.y, true);
  k[0] = a.x; k[1] = a.y; k[2] = b.x; k[3] = b.y;
  v[0] = c.x; v[1] = c.y; v[2] = d.x; v[3] = d.y;
}

// shared attention body: computes this node's 4 output channels (post skip+ELU)
__device__ __forceinline__ float4 attn_body(int nid, int t,
    const int* __restrict__ rowstart, const int* __restrict__ esrc,
    const short* __restrict__ QS, const unsigned char* __restrict__ KV8) {
  const int c0 = t * 4;
  const int r0 = rowstart[nid], r1 = rowstart[nid + 1];
  const float4 q = ld4b(QS + (size_t)nid * 512 + c0);
  const unsigned char* kvb = KV8 + t * 8;
  float m = -INFINITY, denom = 0.f;
  float4 acc = make_float4(0.f, 0.f, 0.f, 0.f);
  int r = r0;
  for (; r + 3 < r1; r += 4) {
    const int2 x0 = *(const int2*)(kvb + (size_t)esrc[r + 0] * 512);
    const int2 x1 = *(const int2*)(kvb + (size_t)esrc[r + 1] * 512);
    const int2 x2 = *(const int2*)(kvb + (size_t)esrc[r + 2] * 512);
    const int2 x3 = *(const int2*)(kvb + (size_t)esrc[r + 3] * 512);
    float k0[4], v0[4], k1[4], v1[4], k2[4], v2[4], k3[4], v3[4];
    dec_kv(x0, k0, v0); dec_kv(x1, k1, v1);
    dec_kv(x2, k2, v2); dec_kv(x3, k3, v3);
    float d0 = q.x * k0[0] + q.y * k0[1] + q.z * k0[2] + q.w * k0[3];
    float d1 = q.x * k1[0] + q.y * k1[1] + q.z * k1[2] + q.w * k1[3];
    float d2 = q.x * k2[0] + q.y * k2[1] + q.z * k2[2] + q.w * k2[3];
    float d3 = q.x * k3[0] + q.y * k3[1] + q.z * k3[2] + q.w * k3[3];
#pragma unroll
    for (int off = 1; off <= 8; off <<= 1) {
      d0 += __shfl_xor(d0, off, 16);
      d1 += __shfl_xor(d1, off, 16);
      d2 += __shfl_xor(d2, off, 16);
      d3 += __shfl_xor(d3, off, 16);
    }
    d0 *= 0.125f; d1 *= 0.125f; d2 *= 0.125f; d3 *= 0.125f;
    const float nm = fmaxf(fmaxf(m, fmaxf(d0, d1)), fmaxf(d2, d3));
    const float sc = __expf(m - nm);
    const float e0 = __expf(d0 - nm);
    const float e1 = __expf(d1 - nm);
    const float e2 = __expf(d2 - nm);
    const float e3 = __expf(d3 - nm);
    denom = denom * sc + e0 + e1 + e2 + e3;
    acc.x = acc.x * sc + e0 * v0[0] + e1 * v1[0] + e2 * v2[0] + e3 * v3[0];
    acc.y = acc.y * sc + e0 * v0[1] + e1 * v1[1] + e2 * v2[1] + e3 * v3[1];
    acc.z = acc.z * sc + e0 * v0[2] + e1 * v1[2] + e2 * v2[2] + e3 * v3[2];
    acc.w = acc.w * sc + e0 * v0[3] + e1 * v1[3] + e2 * v2[3] + e3 * v3[3];
    m = nm;
  }
  for (; r < r1; r++) {
    const int2 x0 = *(const int2*)(kvb + (size_t)esrc[r] * 512);
    float k0[4], v0[4];
    dec_kv(x0, k0, v0);
    float d0 = q.x * k0[0] + q.y * k0[1] + q.z * k0[2] + q.w * k0[3];
#pragma unroll
    for (int off = 1; off <= 8; off <<= 1) d0 += __shfl_xor(d0, off, 16);
    d0 *= 0.125f;
    const float nm = fmaxf(m, d0);
    const float sc = __expf(m - nm);
    const float e0 = __expf(d0 - nm);
    denom = denom * sc + e0;
    acc.x = acc.x * sc + e0 * v0[0];
    acc.y = acc.y * sc + e0 * v0[1];
    acc.z = acc.z * sc + e0 * v0[2];
    acc.w = acc.w * sc + e0 * v0[3];
    m = nm;
  }
  const float inv = 1.0f / (denom + 1e-16f);
  const float4 sk = ld4b(QS + (size_t)nid * 512 + 256 + c0);
  float4 o;
  o.x = acc.x * inv + sk.x;
  o.y = acc.y * inv + sk.y;
  o.z = acc.z * inv + sk.z;
  o.w = acc.w * inv + sk.w;
  o.x = o.x > 0.f ? o.x : expm1f(o.x);
  o.y = o.y > 0.f ? o.y : expm1f(o.y);
  o.z = o.z > 0.f ? o.z : expm1f(o.z);
  o.w = o.w > 0.f ? o.w : expm1f(o.w);
  return o;
}

// ---------- layer-1 attention: write bf16 H1b ----------
__global__ __launch_bounds__(256) void node_attn(
    const int* __restrict__ rowstart, const int* __restrict__ esrc,
    const short* __restrict__ QS, const unsigned char* __restrict__ KV8,
    short* __restrict__ out) {
  const int nid = blockIdx.x * 4 + (threadIdx.x >> 6);
  if (nid >= NN) return;
  const int t = threadIdx.x & 63;
  float4 o = attn_body(nid, t, rowstart, esrc, QS, KV8);
  short4 s; s.x = f2b(o.x); s.y = f2b(o.y); s.z = f2b(o.z); s.w = f2b(o.w);
  *(short4*)(out + (size_t)nid * D1 + t * 4) = s;
}

// ---------- layer-2 attention fused with mean-pool partial sums ----------
// 4 waves/block = 4 consecutive nodes (batch sorted -> usually same graph).
// Wave 0 run-length-merges the 4 node outputs and atomicAdds into sums.
__global__ __launch_bounds__(256) void node_attn_pool(
    const int* __restrict__ rowstart, const int* __restrict__ esrc,
    const short* __restrict__ QS, const unsigned char* __restrict__ KV8,
    const int* __restrict__ batch, float* __restrict__ sums) {
  __shared__ float ob[4][D1];
  __shared__ int og[4];
  const int w = threadIdx.x >> 6;
  const int t = threadIdx.x & 63;
  const int nid = blockIdx.x * 4 + w;     // NN = 4*12500 exactly
  float4 o = attn_body(nid, t, rowstart, esrc, QS, KV8);
  *(float4*)(&ob[w][t * 4]) = o;
  if (t == 0) og[w] = batch[nid];
  __syncthreads();
  if (w != 0) return;
  const int c0 = t * 4;
  float4 run = *(const float4*)(&ob[0][c0]);
  int curg = og[0];
#pragma unroll
  for (int i = 1; i < 4; i++) {
    const int g = og[i];
    const float4 v = *(const float4*)(&ob[i][c0]);
    if (g != curg) {
      float* s = &sums[(size_t)curg * D1 + c0];
      atomicAdd(s + 0, run.x); atomicAdd(s + 1, run.y);
      atomicAdd(s + 2, run.z); atomicAdd(s + 3, run.w);
      run = make_float4(0.f, 0.f, 0.f, 0.f);
      curg = g;
    }
    run.x += v.x; run.y += v.y; run.z += v.z; run.w += v.w;
  }
  float* s = &sums[(size_t)curg * D1 + c0];
  atomicAdd(s + 0, run.x); atomicAdd(s + 1, run.y);
  atomicAdd(s + 2, run.z); atomicAdd(s + 3, run.w);
}

// ---------- classifier + log_softmax (counts from gb) ----------
__global__ __launch_bounds__(640) void head_k(const float* __restrict__ sums,
    const int* __restrict__ gb, const float* __restrict__ Wl,
    const float* __restrict__ bl, float* __restrict__ out) {
  __shared__ float logits[NG][NOUT];
  const int t = threadIdx.x;
  if (t < NG * NOUT) {
    int g = t / NOUT, o = t % NOUT;
    float inv = 1.0f / fmaxf((float)(gb[g + 1] - gb[g]), 1.0f);
    float acc = 0.f;
    for (int k = 0; k < D1; k++) acc += sums[(size_t)g * D1 + k] * Wl[k * NOUT + o];
    logits[g][o] = acc * inv + bl[o];
  }
  __syncthreads();
  if (t < NG) {
    float mx = -INFINITY;
#pragma unroll
    for (int o = 0; o < NOUT; o++) mx = fmaxf(mx, logits[t][o]);
    float s = 0.f;
#pragma unroll
    for (int o = 0; o < NOUT; o++) s += __expf(logits[t][o] - mx);
    float lse = mx + logf(s);
#pragma unroll
    for (int o = 0; o < NOUT; o++) out[t * NOUT + o] = logits[t][o] - lse;
  }
}

// ---------------------------------------------------------------------------
extern "C" void kernel_launch(void* const* d_in, const int* in_sizes, int n_in,
                              void* d_out, int out_size, void* d_ws, size_t ws_size,
                              hipStream_t stream) {
  const float* x   = (const float*)d_in[0];
  const int* ei    = (const int*)d_in[1];
  const int* batch = (const int*)d_in[2];
  const float* Wq1 = (const float*)d_in[3];  const float* bq1 = (const float*)d_in[4];
  const float* Wk1 = (const float*)d_in[5];  const float* bk1 = (const float*)d_in[6];
  const float* Wv1 = (const float*)d_in[7];  const float* bv1 = (const float*)d_in[8];
  const float* Ws1 = (const float*)d_in[9];  const float* bs1 = (const float*)d_in[10];
  const float* Wq2 = (const float*)d_in[11]; const float* bq2 = (const float*)d_in[12];
  const float* Wk2 = (const float*)d_in[13]; const float* bk2 = (const float*)d_in[14];
  const float* Wv2 = (const float*)d_in[15]; const float* bv2 = (const float*)d_in[16];
  const float* Ws2 = (const float*)d_in[17]; const float* bs2 = (const float*)d_in[18];
  const float* Wl  = (const float*)d_in[19]; const float* bl  = (const float*)d_in[20];

  const int* srcIdx = ei;          // edge_index[0] (source j)
  const int* dstIdx = ei + NE;     // edge_index[1] (target i)

  // -------- workspace layout --------
  float* ws = (float*)d_ws;
  float* sums = ws;                              // NG*D1
  float* bc1  = sums + (size_t)NG * D1;          // 1024
  float* bc2  = bc1 + D4;                        // 1024
  short* Xb   = (short*)(bc2 + D4);              // NN*INC
  short* H1b  = Xb + (size_t)NN * INC;           // NN*D1
  short* QS   = H1b + (size_t)NN * D1;           // NN*512 bf16 (Q|S)
  short* Wtc1 = QS + (size_t)NN * 512;           // 1024*128
  short* Wtc2 = Wtc1 + (size_t)D4 * INC;         // 1024*256
  unsigned char* KV8 = (unsigned char*)(Wtc2 + (size_t)D4 * D1);  // NN*512 fp8
  int* ip      = (int*)(KV8 + (size_t)NN * 512);
  int* deg     = ip;                 // NN
  int* partial = deg + NN;           // 256
  int* rowstart= partial + 256;      // NN+1
  int* cursor  = rowstart + NN + 1;  // NN
  int* esrc    = cursor + NN;        // NE
  int* gb      = esrc + NE;          // NG+1

  const int mtiles = (NN + 127) / 128;           // 391
  const dim3 gemmGrid(64, (mtiles + 7) / 8);     // 64 x 49 swizzled
  const int edgeBlocks = (NE + 255) / 256;
  const int aggBlocks  = (NN + 3) / 4;           // 12500 (exact)
  const int cvtBlocks  = CVT_XB + CVT_W1B + CVT_W2B + CVT_BB + CVT_DB + CVT_SB;

  // ======== Converts + zeroing (one kernel) ========
  cvt_all_k<<<cvtBlocks, 256, 0, stream>>>(x, Xb,
      Wq1, Wk1, Wv1, Ws1, Wq2, Wk2, Wv2, Ws2, Wtc1, Wtc2,
      bq1, bk1, bv1, bs1, bq2, bk2, bv2, bs2, bc1, bc2, deg, sums);

  // ======== CSR build + graph bounds ========
  deg_count<<<edgeBlocks, 256, 0, stream>>>(dstIdx, deg);
  scan1<<<NB_SCAN + 1, 256, 0, stream>>>(deg, partial, batch, gb);
  scan3<<<NB_SCAN, 256, 0, stream>>>(deg, partial, rowstart, cursor);
  scatter_k<<<edgeBlocks, 256, 0, stream>>>(srcIdx, dstIdx, cursor, esrc);

  // ======== Layer 1 ========
  gemm_mfma<<<gemmGrid, 256, 0, stream>>>(Xb, Wtc1, bc1, QS, KV8, NN, INC);
  node_attn<<<aggBlocks, 256, 0, stream>>>(rowstart, esrc, QS, KV8, H1b);

  // ======== Layer 2 (attention fused with pool) ========
  gemm_mfma<<<gemmGrid, 256, 0, stream>>>(H1b, Wtc2, bc2, QS, KV8, NN, D1);
  node_attn_pool<<<aggBlocks, 256, 0, stream>>>(rowstart, esrc, QS, KV8, batch, sums);

  // ======== Head ========
  head_k<<<1, 640, 0, stream>>>(sums, gb, Wl, bl, (float*)d_out);
}

// Round 16
// 366.884 us; speedup vs baseline: 1.1436x; 1.1436x over previous
//
#include <hip/hip_runtime.h>
#include <math.h>

constexpr int NN   = 50000;   // nodes
constexpr int NE   = 400000;  // edges
constexpr int INC  = 128;     // in channels
constexpr int NH   = 4;       // heads
constexpr int D1   = 256;     // NH*HIDC
constexpr int D4   = 1024;    // 4*D1 fused QKVS logical cols
constexpr int NOUT = 10;      // classes
constexpr int NG   = 64;      // graphs
constexpr int NB_SCAN = (NN + 255) / 256;   // 196 scan blocks

// GEMM output split per node:
//   QS[node][512] bf16 : cols 0..255 = Q, cols 256..511 = S
//   KV8[node][512] fp8 : byte j -> group g=j>>3, off=j&7: off<4 -> K ch 4g+off,
//                                                        off>=4 -> V ch 4g+(off-4)
// Lane t of node_attn reads 8 B at node*512 + t*8 = [K c0..c0+3 | V c0..c0+3].

typedef __attribute__((ext_vector_type(8))) short bf16x8;   // MFMA A/B frag
typedef __attribute__((ext_vector_type(4))) float f32x4;    // MFMA C/D frag
typedef __attribute__((ext_vector_type(2))) float f32x2;

// ---------- bf16 helpers ----------
__device__ __forceinline__ short f2b(float f) {
  union { float f; unsigned int i; } v; v.f = f;
  unsigned int x = v.i;
  return (short)((x + 0x7FFFu + ((x >> 16) & 1u)) >> 16);
}
__device__ __forceinline__ float b2f(short u) {
  union { unsigned int i; float f; } v; v.i = ((unsigned int)(unsigned short)u) << 16;
  return v.f;
}
__device__ __forceinline__ float4 ld4b(const short* p) {
  short4 u = *(const short4*)p;
  return make_float4(b2f(u.x), b2f(u.y), b2f(u.z), b2f(u.w));
}
__device__ __forceinline__ void unpack8(const int4 v, float* f) {
  union { unsigned int u; float x; } a;
  a.u = (unsigned int)v.x << 16;         f[0] = a.x;
  a.u = (unsigned int)v.x & 0xffff0000u; f[1] = a.x;
  a.u = (unsigned int)v.y << 16;         f[2] = a.x;
  a.u = (unsigned int)v.y & 0xffff0000u; f[3] = a.x;
  a.u = (unsigned int)v.z << 16;         f[4] = a.x;
  a.u = (unsigned int)v.z & 0xffff0000u; f[5] = a.x;
  a.u = (unsigned int)v.w << 16;         f[6] = a.x;
  a.u = (unsigned int)v.w & 0xffff0000u; f[7] = a.x;
}
// pack 4 floats -> 4 fp8 e4m3 bytes (HW convert)
__device__ __forceinline__ int pk_fp8x4(float a, float b, float c, float d) {
  int v = __builtin_amdgcn_cvt_pk_fp8_f32(a, b, 0, false);
  v = __builtin_amdgcn_cvt_pk_fp8_f32(c, d, v, true);
  return v;
}

// ---------- async global->LDS 16B ----------
__device__ __forceinline__ void gld_lds16(const short* g, short* l) {
  __builtin_amdgcn_global_load_lds(
      (const __attribute__((address_space(1))) unsigned int*)g,
      (__attribute__((address_space(3))) unsigned int*)l, 16, 0, 0);
}

// ---------- fused converts + zeroing (one dispatch) ----------
constexpr int CVT_XB  = (NN * INC / 4 + 255) / 256;   // 6250 blocks
constexpr int CVT_W1B = (4 * D1 * INC + 255) / 256;   // 512
constexpr int CVT_W2B = (4 * D1 * D1 + 255) / 256;    // 1024
constexpr int CVT_BB  = 8;                            // bias blocks
constexpr int CVT_DB  = (NN + 255) / 256;             // deg zero (196)
constexpr int CVT_SB  = (NG * D1 + 255) / 256;        // sums zero (64)

__device__ __forceinline__ void wt_one(const float* Wq, const float* Wk,
    const float* Wv, const float* Ws, short* Wt, int kbits, int i) {
  int K = 1 << kbits;
  int seg = i >> (kbits + 8);               // 0=Q 1=K 2=V 3=S
  int idx = i & ((D1 << kbits) - 1);
  int n = idx >> kbits, k = idx & (K - 1);
  const float* W = (seg == 0) ? Wq : (seg == 1) ? Wk : (seg == 2) ? Wv : Ws;
  int row;
  if (seg == 0)      row = n;
  else if (seg == 3) row = 768 + n;
  else               row = 256 + (n >> 2) * 8 + ((seg == 2) ? 4 : 0) + (n & 3);
  Wt[(size_t)row * K + k] = f2b(W[(size_t)k * D1 + n]);
}

__global__ void cvt_all_k(const float* __restrict__ x, short* __restrict__ Xb,
    const float* __restrict__ Wq1, const float* __restrict__ Wk1,
    const float* __restrict__ Wv1, const float* __restrict__ Ws1,
    const float* __restrict__ Wq2, const float* __restrict__ Wk2,
    const float* __restrict__ Wv2, const float* __restrict__ Ws2,
    short* __restrict__ Wtc1, short* __restrict__ Wtc2,
    const float* __restrict__ bq1, const float* __restrict__ bk1,
    const float* __restrict__ bv1, const float* __restrict__ bs1,
    const float* __restrict__ bq2, const float* __restrict__ bk2,
    const float* __restrict__ bv2, const float* __restrict__ bs2,
    float* __restrict__ bc1, float* __restrict__ bc2,
    int* __restrict__ deg, float* __restrict__ sums) {
  const int b = blockIdx.x;
  const int t = threadIdx.x;
  if (b < CVT_XB) {                               // x -> bf16 (4/thread)
    int i = (b * 256 + t) * 4;
    if (i >= NN * INC) return;
    float4 v = *(const float4*)(x + i);
    short4 o; o.x = f2b(v.x); o.y = f2b(v.y); o.z = f2b(v.z); o.w = f2b(v.w);
    *(short4*)(Xb + i) = o;
  } else if (b < CVT_XB + CVT_W1B) {              // layer-1 weights
    int i = (b - CVT_XB) * 256 + t;
    if (i < 4 * D1 * INC) wt_one(Wq1, Wk1, Wv1, Ws1, Wtc1, 7, i);
  } else if (b < CVT_XB + CVT_W1B + CVT_W2B) {    // layer-2 weights
    int i = (b - CVT_XB - CVT_W1B) * 256 + t;
    if (i < 4 * D1 * D1) wt_one(Wq2, Wk2, Wv2, Ws2, Wtc2, 8, i);
  } else if (b < CVT_XB + CVT_W1B + CVT_W2B + CVT_BB) {  // bias concat
    int i = (b - CVT_XB - CVT_W1B - CVT_W2B) * 256 + t;
    if (i >= 2 * D4) return;
    int row = i & (D4 - 1);
    const float* bq = (i < D4) ? bq1 : bq2;
    const float* bk = (i < D4) ? bk1 : bk2;
    const float* bv = (i < D4) ? bv1 : bv2;
    const float* bs = (i < D4) ? bs1 : bs2;
    float v;
    if (row < 256) v = bq[row];
    else if (row < 768) {
      int j = row - 256, grp = j >> 3, off = j & 7;
      int ch = grp * 4 + (off & 3);
      v = (off < 4) ? bk[ch] : bv[ch];
    } else v = bs[row - 768];
    ((i < D4) ? bc1 : bc2)[row] = v;
  } else if (b < CVT_XB + CVT_W1B + CVT_W2B + CVT_BB + CVT_DB) {  // deg = 0
    int i = (b - CVT_XB - CVT_W1B - CVT_W2B - CVT_BB) * 256 + t;
    if (i < NN) deg[i] = 0;
  } else {                                        // sums = 0
    int i = (b - CVT_XB - CVT_W1B - CVT_W2B - CVT_BB - CVT_DB) * 256 + t;
    if (i < NG * D1) sums[i] = 0.f;
  }
}

// ---------- CSR build ----------
__global__ void deg_count(const int* __restrict__ dst, int* __restrict__ deg) {
  int e = blockIdx.x * 256 + threadIdx.x;
  if (e < NE) atomicAdd(&deg[dst[e]], 1);
}
// block partial sums; extra block NB_SCAN does graph bounds (binary search)
__global__ __launch_bounds__(256) void scan1(const int* __restrict__ deg,
    int* __restrict__ partial, const int* __restrict__ batch, int* __restrict__ gb) {
  if (blockIdx.x == NB_SCAN) {
    int g = threadIdx.x;
    if (g > NG) return;
    int lo = 0, hi = NN;
    while (lo < hi) {
      int mid = (lo + hi) >> 1;
      if (batch[mid] < g) lo = mid + 1; else hi = mid;
    }
    gb[g] = lo;
    return;
  }
  __shared__ int sh[256];
  int t = threadIdx.x, i = blockIdx.x * 256 + t;
  sh[t] = (i < NN) ? deg[i] : 0;
  __syncthreads();
  for (int off = 128; off > 0; off >>= 1) {
    if (t < off) sh[t] += sh[t + off];
    __syncthreads();
  }
  if (t == 0) partial[blockIdx.x] = sh[0];
}
__global__ __launch_bounds__(256) void scan3(const int* __restrict__ deg,
    const int* __restrict__ partial, int* __restrict__ rowstart,
    int* __restrict__ cursor) {
  __shared__ int sh[256];
  __shared__ int base_s;
  const int t = threadIdx.x;
  int pv = (t < NB_SCAN) ? partial[t] : 0;
  sh[t] = pv;
  __syncthreads();
  for (int off = 1; off < 256; off <<= 1) {
    int o = (t >= off) ? sh[t - off] : 0;
    __syncthreads();
    sh[t] += o;
    __syncthreads();
  }
  if (t == 0) base_s = (blockIdx.x == 0) ? 0 : sh[blockIdx.x - 1];
  __syncthreads();
  const int base = base_s;
  __syncthreads();
  int i = blockIdx.x * 256 + t;
  int v = (i < NN) ? deg[i] : 0;
  sh[t] = v;
  __syncthreads();
  for (int off = 1; off < 256; off <<= 1) {
    int o = (t >= off) ? sh[t - off] : 0;
    __syncthreads();
    sh[t] += o;
    __syncthreads();
  }
  int excl = sh[t] - v + base;
  if (i <= NN) rowstart[i] = excl;
  if (i < NN)  cursor[i]   = excl;
}
__global__ void scatter_k(const int* __restrict__ src, const int* __restrict__ dst,
    int* __restrict__ cursor, int* __restrict__ esrc) {
  int e = blockIdx.x * 256 + threadIdx.x;
  if (e >= NE) return;
  int d = dst[e];
  int pos = atomicAdd(&cursor[d], 1);
  esrc[pos] = src[e];
}

// ---------- MFMA GEMM: [QS bf16 | KV8 fp8] = Xb[M,K] @ Wt[1024,K]^T + bias ----
constexpr int CLDS = 136;   // C-tile LDS stride in shorts

__global__ __launch_bounds__(256) void gemm_mfma(
    const short* __restrict__ Xb, const short* __restrict__ Wt,
    const float* __restrict__ bias, short* __restrict__ QS,
    unsigned char* __restrict__ KV8, int M, int K) {
  __shared__ short smem[128 * CLDS];
  short* As0 = smem;
  short* As1 = smem + 4096;
  short* Bs0 = smem + 8192;
  short* Bs1 = smem + 12288;
  const int bx = blockIdx.x;                 // 0..63
  const int by = blockIdx.y;
  const int m_tile = (bx & 7) + (by << 3);   // XCD swizzle
  const int n_tile = bx >> 3;                // 0..7
  const int m0 = m_tile * 128;
  if (m0 >= M) return;
  const int n0 = n_tile * 128;

  const int t    = threadIdx.x;
  const int lane = t & 63;
  const int wv   = t >> 6;
  const int wm   = (wv >> 1) * 64;
  const int wn   = (wv & 1) * 64;
  const int quad = lane >> 4;
  const int l16  = lane & 15;
  const int lrow = lane >> 2;
  const int lseg = lane & 3;

  f32x4 acc[4][4] = {};
  for (int k0 = 0; k0 < K; k0 += 64) {
#pragma unroll
    for (int j = 0; j < 2; ++j) {
      const int rb = wv * 32 + j * 16;
      int gm = m0 + rb + lrow;
      gm = gm < M ? gm : M - 1;                        // clamp (stores guarded)
      const size_t ga = (size_t)gm * K + k0 + lseg * 8;
      gld_lds16(Xb + ga,      &As0[rb * 32]);
      gld_lds16(Xb + ga + 32, &As1[rb * 32]);
      const size_t gw = (size_t)(n0 + rb + lrow) * K + k0 + lseg * 8;
      gld_lds16(Wt + gw,      &Bs0[rb * 32]);
      gld_lds16(Wt + gw + 32, &Bs1[rb * 32]);
    }
    __syncthreads();
    {
      bf16x8 a[4], b[4];
#pragma unroll
      for (int mi = 0; mi < 4; mi++)
        a[mi] = *(const bf16x8*)(&As0[(wm + mi * 16 + l16) * 32 + quad * 8]);
#pragma unroll
      for (int nj = 0; nj < 4; nj++)
        b[nj] = *(const bf16x8*)(&Bs0[(wn + nj * 16 + l16) * 32 + quad * 8]);
#pragma unroll
      for (int mi = 0; mi < 4; mi++)
#pragma unroll
        for (int nj = 0; nj < 4; nj++)
          acc[mi][nj] = __builtin_amdgcn_mfma_f32_16x16x32_bf16(a[mi], b[nj], acc[mi][nj], 0, 0, 0);
#pragma unroll
      for (int mi = 0; mi < 4; mi++)
        a[mi] = *(const bf16x8*)(&As1[(wm + mi * 16 + l16) * 32 + quad * 8]);
#pragma unroll
      for (int nj = 0; nj < 4; nj++)
        b[nj] = *(const bf16x8*)(&Bs1[(wn + nj * 16 + l16) * 32 + quad * 8]);
#pragma unroll
      for (int mi = 0; mi < 4; mi++)
#pragma unroll
        for (int nj = 0; nj < 4; nj++)
          acc[mi][nj] = __builtin_amdgcn_mfma_f32_16x16x32_bf16(a[mi], b[nj], acc[mi][nj], 0, 0, 0);
    }
    __syncthreads();
  }
  // ---- epilogue: stage bf16 C tile in LDS, then coalesced typed stores ----
  float bcol[4];
#pragma unroll
  for (int nj = 0; nj < 4; nj++) bcol[nj] = bias[n0 + wn + nj * 16 + l16];
#pragma unroll
  for (int mi = 0; mi < 4; mi++)
#pragma unroll
    for (int r = 0; r < 4; r++) {
      const int row = wm + mi * 16 + quad * 4 + r;
#pragma unroll
      for (int nj = 0; nj < 4; nj++)
        smem[row * CLDS + wn + nj * 16 + l16] = f2b(acc[mi][nj][r] + bcol[nj]);
    }
  __syncthreads();
  const bool isKV = (n_tile >= 2) && (n_tile <= 5);
  const int qs_base = (n_tile < 2) ? n0 : (n0 - 512);   // Q cols or S cols
  const int kv_base = n0 - 256;
#pragma unroll
  for (int it = 0; it < 8; ++it) {
    const int chunk = it * 256 + t;          // 2048 chunks of 8 shorts
    const int row = chunk >> 4;
    const int cc  = (chunk & 15) * 8;
    const int gm  = m0 + row;
    if (gm >= M) continue;
    const int4 s4 = *(const int4*)(&smem[row * CLDS + cc]);
    if (isKV) {
      float f[8];
      unpack8(s4, f);
      int lo = pk_fp8x4(f[0], f[1], f[2], f[3]);
      int hi = pk_fp8x4(f[4], f[5], f[6], f[7]);
      *(int2*)(KV8 + (size_t)gm * 512 + kv_base + cc) = make_int2(lo, hi);
    } else {
      *(int4*)(QS + (size_t)gm * 512 + qs_base + cc) = s4;
    }
  }
}

// ---------- fp8 KV decode ----------
__device__ __forceinline__ void dec_kv(const int2 x, float* k, float* v) {
  f32x2 a = __builtin_amdgcn_cvt_pk_f32_fp8(x.x, false);
  f32x2 b = __builtin_amdgcn_cvt_pk_f32_fp8(x.x, true);
  f32x2 c = __builtin_amdgcn_cvt_pk_f32_fp8(x.y, false);
  f32x2 d = __builtin_amdgcn_cvt_pk_f32_fp8(x.y, true);
  k[0] = a.x; k[1] = a.y; k[2] = b.x; k[3] = b.y;
  v[0] = c.x; v[1] = c.y; v[2] = d.x; v[3] = d.y;
}

// ---------- fused attention: online softmax, fp8 KV, 4-edge unroll ----------
template <typename TOUT>
__device__ __forceinline__ void st1(TOUT* p, float v);
template <> __device__ __forceinline__ void st1<float>(float* p, float v) { *p = v; }
template <> __device__ __forceinline__ void st1<short>(short* p, float v) { *p = f2b(v); }

template <typename TOUT>
__global__ __launch_bounds__(256) void node_attn(
    const int* __restrict__ rowstart, const int* __restrict__ esrc,
    const short* __restrict__ QS, const unsigned char* __restrict__ KV8,
    TOUT* __restrict__ out) {
  const int nid = blockIdx.x * 4 + (threadIdx.x >> 6);
  if (nid >= NN) return;
  const int t  = threadIdx.x & 63;
  const int c0 = t * 4;
  const int r0 = rowstart[nid], r1 = rowstart[nid + 1];
  const float4 q = ld4b(QS + (size_t)nid * 512 + c0);
  const unsigned char* kvb = KV8 + t * 8;
  float m = -INFINITY, denom = 0.f;
  float4 acc = make_float4(0.f, 0.f, 0.f, 0.f);
  int r = r0;
  for (; r + 3 < r1; r += 4) {
    const int2 x0 = *(const int2*)(kvb + (size_t)esrc[r + 0] * 512);
    const int2 x1 = *(const int2*)(kvb + (size_t)esrc[r + 1] * 512);
    const int2 x2 = *(const int2*)(kvb + (size_t)esrc[r + 2] * 512);
    const int2 x3 = *(const int2*)(kvb + (size_t)esrc[r + 3] * 512);
    float k0[4], v0[4], k1[4], v1[4], k2[4], v2[4], k3[4], v3[4];
    dec_kv(x0, k0, v0); dec_kv(x1, k1, v1);
    dec_kv(x2, k2, v2); dec_kv(x3, k3, v3);
    float d0 = q.x * k0[0] + q.y * k0[1] + q.z * k0[2] + q.w * k0[3];
    float d1 = q.x * k1[0] + q.y * k1[1] + q.z * k1[2] + q.w * k1[3];
    float d2 = q.x * k2[0] + q.y * k2[1] + q.z * k2[2] + q.w * k2[3];
    float d3 = q.x * k3[0] + q.y * k3[1] + q.z * k3[2] + q.w * k3[3];
#pragma unroll
    for (int off = 1; off <= 8; off <<= 1) {
      d0 += __shfl_xor(d0, off, 16);
      d1 += __shfl_xor(d1, off, 16);
      d2 += __shfl_xor(d2, off, 16);
      d3 += __shfl_xor(d3, off, 16);
    }
    d0 *= 0.125f; d1 *= 0.125f; d2 *= 0.125f; d3 *= 0.125f;
    const float nm = fmaxf(fmaxf(m, fmaxf(d0, d1)), fmaxf(d2, d3));
    const float sc = __expf(m - nm);
    const float e0 = __expf(d0 - nm);
    const float e1 = __expf(d1 - nm);
    const float e2 = __expf(d2 - nm);
    const float e3 = __expf(d3 - nm);
    denom = denom * sc + e0 + e1 + e2 + e3;
    acc.x = acc.x * sc + e0 * v0[0] + e1 * v1[0] + e2 * v2[0] + e3 * v3[0];
    acc.y = acc.y * sc + e0 * v0[1] + e1 * v1[1] + e2 * v2[1] + e3 * v3[1];
    acc.z = acc.z * sc + e0 * v0[2] + e1 * v1[2] + e2 * v2[2] + e3 * v3[2];
    acc.w = acc.w * sc + e0 * v0[3] + e1 * v1[3] + e2 * v2[3] + e3 * v3[3];
    m = nm;
  }
  for (; r < r1; r++) {
    const int2 x0 = *(const int2*)(kvb + (size_t)esrc[r] * 512);
    float k0[4], v0[4];
    dec_kv(x0, k0, v0);
    float d0 = q.x * k0[0] + q.y * k0[1] + q.z * k0[2] + q.w * k0[3];
#pragma unroll
    for (int off = 1; off <= 8; off <<= 1) d0 += __shfl_xor(d0, off, 16);
    d0 *= 0.125f;
    const float nm = fmaxf(m, d0);
    const float sc = __expf(m - nm);
    const float e0 = __expf(d0 - nm);
    denom = denom * sc + e0;
    acc.x = acc.x * sc + e0 * v0[0];
    acc.y = acc.y * sc + e0 * v0[1];
    acc.z = acc.z * sc + e0 * v0[2];
    acc.w = acc.w * sc + e0 * v0[3];
    m = nm;
  }
  const float inv = 1.0f / (denom + 1e-16f);
  const float4 sk = ld4b(QS + (size_t)nid * 512 + 256 + c0);
  float o0 = acc.x * inv + sk.x;
  float o1 = acc.y * inv + sk.y;
  float o2 = acc.z * inv + sk.z;
  float o3 = acc.w * inv + sk.w;
  o0 = o0 > 0.f ? o0 : expm1f(o0);
  o1 = o1 > 0.f ? o1 : expm1f(o1);
  o2 = o2 > 0.f ? o2 : expm1f(o2);
  o3 = o3 > 0.f ? o3 : expm1f(o3);
  TOUT* p = out + (size_t)nid * D1 + c0;
  st1<TOUT>(p + 0, o0); st1<TOUT>(p + 1, o1);
  st1<TOUT>(p + 2, o2); st1<TOUT>(p + 3, o3);
}

// ---------- mean-pool partial sums (parallel, run-length atomics) ----------
__global__ __launch_bounds__(256) void pool_k(const float* __restrict__ h,
    const int* __restrict__ batch, float* __restrict__ sums) {
  const int c = threadIdx.x;
  const int n0 = blockIdx.x * 64;
  const int n1 = min(n0 + 64, NN);
  float run = 0.f;
  int curg = -1;
  for (int n = n0; n < n1; n++) {
    int g = batch[n];
    if (g != curg) {
      if (curg >= 0) atomicAdd(&sums[(size_t)curg * D1 + c], run);
      run = 0.f; curg = g;
    }
    run += h[(size_t)n * D1 + c];
  }
  if (curg >= 0) atomicAdd(&sums[(size_t)curg * D1 + c], run);
}

// ---------- classifier + log_softmax (counts from gb) ----------
__global__ __launch_bounds__(640) void head_k(const float* __restrict__ sums,
    const int* __restrict__ gb, const float* __restrict__ Wl,
    const float* __restrict__ bl, float* __restrict__ out) {
  __shared__ float logits[NG][NOUT];
  const int t = threadIdx.x;
  if (t < NG * NOUT) {
    int g = t / NOUT, o = t % NOUT;
    float inv = 1.0f / fmaxf((float)(gb[g + 1] - gb[g]), 1.0f);
    float acc = 0.f;
    for (int k = 0; k < D1; k++) acc += sums[(size_t)g * D1 + k] * Wl[k * NOUT + o];
    logits[g][o] = acc * inv + bl[o];
  }
  __syncthreads();
  if (t < NG) {
    float mx = -INFINITY;
#pragma unroll
    for (int o = 0; o < NOUT; o++) mx = fmaxf(mx, logits[t][o]);
    float s = 0.f;
#pragma unroll
    for (int o = 0; o < NOUT; o++) s += __expf(logits[t][o] - mx);
    float lse = mx + logf(s);
#pragma unroll
    for (int o = 0; o < NOUT; o++) out[t * NOUT + o] = logits[t][o] - lse;
  }
}

// ---------------------------------------------------------------------------
extern "C" void kernel_launch(void* const* d_in, const int* in_sizes, int n_in,
                              void* d_out, int out_size, void* d_ws, size_t ws_size,
                              hipStream_t stream) {
  const float* x   = (const float*)d_in[0];
  const int* ei    = (const int*)d_in[1];
  const int* batch = (const int*)d_in[2];
  const float* Wq1 = (const float*)d_in[3];  const float* bq1 = (const float*)d_in[4];
  const float* Wk1 = (const float*)d_in[5];  const float* bk1 = (const float*)d_in[6];
  const float* Wv1 = (const float*)d_in[7];  const float* bv1 = (const float*)d_in[8];
  const float* Ws1 = (const float*)d_in[9];  const float* bs1 = (const float*)d_in[10];
  const float* Wq2 = (const float*)d_in[11]; const float* bq2 = (const float*)d_in[12];
  const float* Wk2 = (const float*)d_in[13]; const float* bk2 = (const float*)d_in[14];
  const float* Wv2 = (const float*)d_in[15]; const float* bv2 = (const float*)d_in[16];
  const float* Ws2 = (const float*)d_in[17]; const float* bs2 = (const float*)d_in[18];
  const float* Wl  = (const float*)d_in[19]; const float* bl  = (const float*)d_in[20];

  const int* srcIdx = ei;          // edge_index[0] (source j)
  const int* dstIdx = ei + NE;     // edge_index[1] (target i)

  // -------- workspace layout --------
  float* ws = (float*)d_ws;
  const size_t SZ_NODE = (size_t)NN * D1;       // 12.8M elems
  float* H2f  = ws;                              // NN*D1 fp32
  float* sums = ws + SZ_NODE;                    // NG*D1
  float* bc1  = sums + (size_t)NG * D1;          // 1024
  float* bc2  = bc1 + D4;                        // 1024
  short* Xb   = (short*)(bc2 + D4);              // NN*INC
  short* H1b  = Xb + (size_t)NN * INC;           // NN*D1
  short* QS   = H1b + SZ_NODE;                   // NN*512 bf16 (Q|S)
  short* Wtc1 = QS + (size_t)NN * 512;           // 1024*128
  short* Wtc2 = Wtc1 + (size_t)D4 * INC;         // 1024*256
  unsigned char* KV8 = (unsigned char*)(Wtc2 + (size_t)D4 * D1);  // NN*512 fp8
  int* ip      = (int*)(KV8 + (size_t)NN * 512);
  int* deg     = ip;                 // NN
  int* partial = deg + NN;           // 256
  int* rowstart= partial + 256;      // NN+1
  int* cursor  = rowstart + NN + 1;  // NN
  int* esrc    = cursor + NN;        // NE
  int* gb      = esrc + NE;          // NG+1

  const int mtiles = (NN + 127) / 128;           // 391
  const dim3 gemmGrid(64, (mtiles + 7) / 8);     // 64 x 49 swizzled
  const int edgeBlocks = (NE + 255) / 256;
  const int aggBlocks  = (NN + 3) / 4;
  const int cvtBlocks  = CVT_XB + CVT_W1B + CVT_W2B + CVT_BB + CVT_DB + CVT_SB;

  // ======== Converts + zeroing (one kernel) ========
  cvt_all_k<<<cvtBlocks, 256, 0, stream>>>(x, Xb,
      Wq1, Wk1, Wv1, Ws1, Wq2, Wk2, Wv2, Ws2, Wtc1, Wtc2,
      bq1, bk1, bv1, bs1, bq2, bk2, bv2, bs2, bc1, bc2, deg, sums);

  // ======== CSR build + graph bounds ========
  deg_count<<<edgeBlocks, 256, 0, stream>>>(dstIdx, deg);
  scan1<<<NB_SCAN + 1, 256, 0, stream>>>(deg, partial, batch, gb);
  scan3<<<NB_SCAN, 256, 0, stream>>>(deg, partial, rowstart, cursor);
  scatter_k<<<edgeBlocks, 256, 0, stream>>>(srcIdx, dstIdx, cursor, esrc);

  // ======== Layer 1 ========
  gemm_mfma<<<gemmGrid, 256, 0, stream>>>(Xb, Wtc1, bc1, QS, KV8, NN, INC);
  node_attn<short><<<aggBlocks, 256, 0, stream>>>(rowstart, esrc, QS, KV8, H1b);

  // ======== Layer 2 ========
  gemm_mfma<<<gemmGrid, 256, 0, stream>>>(H1b, Wtc2, bc2, QS, KV8, NN, D1);
  node_attn<float><<<aggBlocks, 256, 0, stream>>>(rowstart, esrc, QS, KV8, H2f);

  // ======== Pool + head ========
  pool_k<<<(NN + 63) / 64, 256, 0, stream>>>(H2f, batch, sums);
  head_k<<<1, 640, 0, stream>>>(sums, gb, Wl, bl, (float*)d_out);
}